// Round 6
// baseline (160.614 us; speedup 1.0000x reference)
//
#include <hip/hip_runtime.h>
#include <stdint.h>

#define DEVINL __device__ __forceinline__

typedef float f32x4 __attribute__((ext_vector_type(4)));
typedef float f32x2 __attribute__((ext_vector_type(2)));
typedef short s16x8 __attribute__((ext_vector_type(8)));
typedef short s16x4 __attribute__((ext_vector_type(4)));
typedef unsigned int u32x4 __attribute__((ext_vector_type(4)));

constexpr int Bb = 4, Hh = 16, Ss = 2048, Dd = 64;
constexpr float SCALE = 0.088388347648318447f;                     // 1/sqrt(128)
constexpr float QSC = 0.088388347648318447f * 1.4426950408889634f; // scale * log2(e)

DEVINL short f2bf(float x) {
  union { float f; unsigned u; } c; c.f = x;
  unsigned r = (c.u + 0x7fffu + ((c.u >> 16) & 1u)) >> 16;  // RNE
  return (short)r;
}

DEVINL unsigned pkbf(float a, float b) {
  unsigned r;
  asm("v_cvt_pk_bf16_f32 %0, %1, %2" : "=v"(r) : "v"(a), "v"(b));
  return r;
}

// ---------------- fused prepass ----------------
// blocks [0,4096): K/V -> FRAGMENT-MAJOR bf16 images (per bh,tile: 4096 shorts;
//   frag f (0..7), lane (0..63), elem j: img[(f*64+lane)*8 + j])
//   K: frag f=(sub,h): value = K[t*64 + (f>>1)*16 + (lane&15)][ d ],
//      d = P/4 + (j>>2) + 16*(j&3), P = 16*(lane>>4) + 8*(f&1)
//   V: frag f=(ds,h):  value = V[t*64 + kv][ (f>>1)*16 + (lane&15) ],
//      kv = P/4 + (j>>2) + 16*(j&3)
// blocks [4096,5120): mask -> bitmask (64 mask ints -> one u64)
__global__ void prep(const float* __restrict__ K, const float* __restrict__ V,
                     const int* __restrict__ mask,
                     short* __restrict__ Kimg, short* __restrict__ Vimg,
                     unsigned long long* __restrict__ bits) {
  const int x = blockIdx.x;
  const int tid = threadIdx.x;
  if (x < 4096) {
    const int sel = x & 1;
    const int t = (x >> 1) & 31;
    const int bh = x >> 6;
    short* img = (sel ? Vimg : Kimg) + ((size_t)bh * 32 + t) * 4096;
    const float* src = (sel ? V : K) + (size_t)bh * Ss * Dd;
#pragma unroll
    for (int p = 0; p < 2; ++p) {
      const int pr = tid + p * 256;   // 0..511 = (frag, lane)
      const int f = pr >> 6;
      const int lane = pr & 63;
      const int l15 = lane & 15, lq = lane >> 4;
      const int P = 16 * lq + 8 * (f & 1);
      const int fs = f >> 1;
      s16x8 o;
      if (sel == 0) {
        const float* kr = src + (size_t)(t * 64 + fs * 16 + l15) * Dd + (P >> 2);
#pragma unroll
        for (int jj = 0; jj < 2; ++jj)
#pragma unroll
          for (int m = 0; m < 4; ++m)
            o[jj * 4 + m] = f2bf(kr[jj + 16 * m]);
      } else {
        const float* vc = src + (size_t)(t * 64 + (P >> 2)) * Dd + fs * 16 + l15;
#pragma unroll
        for (int jj = 0; jj < 2; ++jj)
#pragma unroll
          for (int m = 0; m < 4; ++m)
            o[jj * 4 + m] = f2bf(vc[(size_t)(jj + 16 * m) * Dd]);
      }
      *(s16x8*)(img + pr * 8) = o;
    }
  } else {
    const int gid = (x - 4096) * 256 + tid;
    const int stride = 1024 * 256;
    const int n = Bb * Ss * Ss;
    for (int i = gid; i < n; i += stride) {
      unsigned long long bal = __ballot(mask[i] != 0);
      if ((i & 63) == 0) bits[i >> 6] = bal;
    }
  }
}

// ---------------- main attention kernel: no LDS, no barriers ----------------
// 4 waves x 64 q-rows (q-tile 256), grid 512, XCD-bijective swizzle keeps each
// bh's 512KB image set in one XCD L2. Fragments loaded dwordx4 straight from
// the fragment-major images; K(t+1)/V(t+1) prefetched into freed registers.
// Mask folded into QK^T C-init (0 keep / -1e9 drop, log2 domain); exp2-only
// softmax; row-sum l via ones-row MFMA.
__launch_bounds__(256, 2)
__global__ void attn3(const float* __restrict__ Q,
                      const unsigned long long* __restrict__ mbits,
                      const short* __restrict__ Kimg,
                      const short* __restrict__ Vimg,
                      float* __restrict__ Out) {
  const int tid = threadIdx.x;
  const int lane = tid & 63;
  const int w = tid >> 6;
  const int l15 = lane & 15;
  const int lq = lane >> 4;

  // bijective XCD swizzle: 512 = 8 * 64
  const int nb = ((blockIdx.x & 7) << 6) | (blockIdx.x >> 3);
  const int qt = nb & 7;        // 8 q-tiles of 256
  const int bh = nb >> 3;
  const int b = bh >> 4;

  const float* Qp = Q + (size_t)bh * Ss * Dd;
  float* Op = Out + (size_t)bh * Ss * Dd;
  const short* Kt = Kimg + (size_t)bh * 32 * 4096 + lane * 8;
  const short* Vt = Vimg + (size_t)bh * 32 * 4096 + lane * 8;
  const int qbW = qt * 256 + w * 64;

  // Q fragments (B-operand), scale*log2e folded in
  s16x8 qf[4][2];
#pragma unroll
  for (int qs = 0; qs < 4; ++qs) {
    const float* qrow = Qp + (size_t)(qbW + qs * 16 + l15) * Dd;
#pragma unroll
    for (int dh = 0; dh < 2; ++dh) {
      s16x8 f;
#pragma unroll
      for (int g = 0; g < 4; ++g) {
        f32x2 v = *(const f32x2*)(qrow + 16 * g + 4 * lq + 2 * dh);
        f[g] = f2bf(v[0] * QSC);
        f[g + 4] = f2bf(v[1] * QSC);
      }
      qf[qs][dh] = f;
    }
  }

  // constant ones A-fragment: row 0 = 1.0bf16, rows 1..15 = 0 (k-map agnostic)
  s16x8 onesA;
  {
    short o = (l15 == 0) ? (short)0x3F80 : (short)0;
#pragma unroll
    for (int j = 0; j < 8; ++j) onesA[j] = o;
  }

  f32x4 oacc[4][4];
  f32x4 lacc[4];
#pragma unroll
  for (int qs = 0; qs < 4; ++qs) {
    lacc[qs] = f32x4{0.f, 0.f, 0.f, 0.f};
#pragma unroll
    for (int ds = 0; ds < 4; ++ds) oacc[qs][ds] = f32x4{0.f, 0.f, 0.f, 0.f};
  }

  const unsigned long long* mbq = mbits + (size_t)(b * Ss + qbW + l15) * 32;

  // prologue: tile 0 fragments
  s16x8 kf[8], vf[8];
#pragma unroll
  for (int f = 0; f < 8; ++f) kf[f] = *(const s16x8*)(Kt + f * 512);
#pragma unroll
  for (int f = 0; f < 8; ++f) vf[f] = *(const s16x8*)(Vt + f * 512);

  for (int t = 0; t < 32; ++t) {
    // mask words (one per qs; row q = qbW + qs*16 + l15)
    unsigned long long mw[4];
#pragma unroll
    for (int qs = 0; qs < 4; ++qs) mw[qs] = mbq[qs * 512 + t];

    // ---- mask bias straight into the score accumulators
    f32x4 sc[4][4];
#pragma unroll
    for (int qs = 0; qs < 4; ++qs) {
      const unsigned mlo = ~(unsigned)(mw[qs] >> (4 * lq));
      const unsigned mhi = ~(unsigned)(mw[qs] >> (32 + 4 * lq));
#pragma unroll
      for (int sub = 0; sub < 4; ++sub) {
        const unsigned wsrc = (sub < 2) ? mlo : mhi;
        const int base = 16 * (sub & 1);
#pragma unroll
        for (int r = 0; r < 4; ++r) {
          int sb = ((int)(wsrc << (31 - (base + r)))) >> 31;  // keep -> 0, drop -> -1
          sc[qs][sub][r] = __uint_as_float((unsigned)sb & 0xCE6E6B28u);  // 0 or -1e9
        }
      }
    }

    // ---- QK^T (S^T = K*Q^T)
    __builtin_amdgcn_s_setprio(1);
#pragma unroll
    for (int sub = 0; sub < 4; ++sub)
#pragma unroll
      for (int qs = 0; qs < 4; ++qs) {
        sc[qs][sub] = __builtin_amdgcn_mfma_f32_16x16x32_bf16(kf[sub * 2], qf[qs][0], sc[qs][sub], 0, 0, 0);
        sc[qs][sub] = __builtin_amdgcn_mfma_f32_16x16x32_bf16(kf[sub * 2 + 1], qf[qs][1], sc[qs][sub], 0, 0, 0);
      }
    __builtin_amdgcn_s_setprio(0);

    // prefetch K(t+1) into freed kf regs (latency hidden by exp2+PV)
    if (t < 31) {
      const short* nk = Kt + (t + 1) * 4096;
#pragma unroll
      for (int f = 0; f < 8; ++f) kf[f] = *(const s16x8*)(nk + f * 512);
    }

    // ---- softmax numerator: exp2 only + P->bf16
    s16x8 pf[4][2];
#pragma unroll
    for (int qs = 0; qs < 4; ++qs) {
#pragma unroll
      for (int sub = 0; sub < 4; ++sub) {
        f32x4 s = sc[qs][sub];
#pragma unroll
        for (int r = 0; r < 4; ++r) s[r] = __builtin_amdgcn_exp2f(s[r]);
        sc[qs][sub] = s;
      }
#pragma unroll
      for (int kvh = 0; kvh < 2; ++kvh) {
        u32x4 wv;
        wv[0] = pkbf(sc[qs][0][2 * kvh], sc[qs][1][2 * kvh]);
        wv[1] = pkbf(sc[qs][2][2 * kvh], sc[qs][3][2 * kvh]);
        wv[2] = pkbf(sc[qs][0][2 * kvh + 1], sc[qs][1][2 * kvh + 1]);
        wv[3] = pkbf(sc[qs][2][2 * kvh + 1], sc[qs][3][2 * kvh + 1]);
        pf[qs][kvh] = __builtin_bit_cast(s16x8, wv);
      }
    }

    // ---- PV (O^T += V^T * P^T) + l via ones-row MFMA
    __builtin_amdgcn_s_setprio(1);
#pragma unroll
    for (int ds = 0; ds < 4; ++ds)
#pragma unroll
      for (int qs = 0; qs < 4; ++qs) {
        oacc[qs][ds] = __builtin_amdgcn_mfma_f32_16x16x32_bf16(vf[ds * 2], pf[qs][0], oacc[qs][ds], 0, 0, 0);
        oacc[qs][ds] = __builtin_amdgcn_mfma_f32_16x16x32_bf16(vf[ds * 2 + 1], pf[qs][1], oacc[qs][ds], 0, 0, 0);
      }
#pragma unroll
    for (int qs = 0; qs < 4; ++qs) {
      lacc[qs] = __builtin_amdgcn_mfma_f32_16x16x32_bf16(onesA, pf[qs][0], lacc[qs], 0, 0, 0);
      lacc[qs] = __builtin_amdgcn_mfma_f32_16x16x32_bf16(onesA, pf[qs][1], lacc[qs], 0, 0, 0);
    }
    __builtin_amdgcn_s_setprio(0);

    // prefetch V(t+1)
    if (t < 31) {
      const short* nv = Vt + (t + 1) * 4096;
#pragma unroll
      for (int f = 0; f < 8; ++f) vf[f] = *(const s16x8*)(nv + f * 512);
    }
  }

  // epilogue: l lives in row 0 (lanes lq==0, reg 0); broadcast, divide, store
#pragma unroll
  for (int qs = 0; qs < 4; ++qs) {
    float l = __shfl(lacc[qs][0], l15);
    float inv = 1.f / l;
    float* orow = Op + (size_t)(qbW + qs * 16 + l15) * Dd;
#pragma unroll
    for (int ds = 0; ds < 4; ++ds) {
      f32x4 v = oacc[qs][ds];
      v *= inv;
      *(f32x4*)(orow + ds * 16 + 4 * lq) = v;
    }
  }
}

// ---------------- fallback (round-1 kernel, proven) ----------------
__global__ void mask_to_bits(const int* __restrict__ mask,
                             unsigned long long* __restrict__ bits, int n) {
  int gid = blockIdx.x * blockDim.x + threadIdx.x;
  int stride = gridDim.x * blockDim.x;
  for (int i = gid; i < n; i += stride) {
    unsigned long long bal = __ballot(mask[i] != 0);
    if ((i & 63) == 0) bits[i >> 6] = bal;
  }
}

template<bool USEBITS>
__launch_bounds__(256, 2)
__global__ void attn_fwd(const float* __restrict__ Q, const float* __restrict__ K,
                         const float* __restrict__ V, const int* __restrict__ mask,
                         const unsigned long long* __restrict__ mbits,
                         float* __restrict__ Out) {
  __shared__ short Ks[64 * 64];
  __shared__ short Vs[64 * 64];

  const int tid = threadIdx.x;
  const int lane = tid & 63;
  const int w = tid >> 6;
  const int l15 = lane & 15;
  const int lq = lane >> 4;

  const int bid = blockIdx.x;
  const int h = bid & 15;
  const int qt = (bid >> 4) & 7;
  const int b = bid >> 7;

  const int bh = b * Hh + h;
  const float* Qp = Q + (size_t)bh * Ss * Dd;
  const float* Kp = K + (size_t)bh * Ss * Dd;
  const float* Vp = V + (size_t)bh * Ss * Dd;
  float* Op = Out + (size_t)bh * Ss * Dd;

  const int qbW = qt * 256 + w * 64;

  s16x8 qf[4][2];
#pragma unroll
  for (int qs = 0; qs < 4; ++qs) {
    const float* qrow = Qp + (size_t)(qbW + qs * 16 + l15) * Dd;
#pragma unroll
    for (int dh = 0; dh < 2; ++dh) {
      s16x8 f;
#pragma unroll
      for (int g = 0; g < 4; ++g) {
        f32x2 v = *(const f32x2*)(qrow + 16 * g + 4 * lq + 2 * dh);
        f[g] = f2bf(v[0]);
        f[g + 4] = f2bf(v[1]);
      }
      qf[qs][dh] = f;
    }
  }

  f32x4 oacc[4][4];
  float mrun[4], lrun[4];
#pragma unroll
  for (int qs = 0; qs < 4; ++qs) {
    mrun[qs] = -1e30f;
    lrun[qs] = 0.f;
#pragma unroll
    for (int ds = 0; ds < 4; ++ds) oacc[qs][ds] = f32x4{0.f, 0.f, 0.f, 0.f};
  }

  for (int kv0 = 0; kv0 < Ss; kv0 += 64) {
    __syncthreads();
#pragma unroll
    for (int p = 0; p < 4; ++p) {
      int f = tid + p * 256;
      int kv = f >> 4;
      int c = f & 15;
      const float* krow = Kp + (size_t)(kv0 + kv) * Dd;
      s16x4 sv;
      sv[0] = f2bf(krow[c]);
      sv[1] = f2bf(krow[c + 16]);
      sv[2] = f2bf(krow[c + 32]);
      sv[3] = f2bf(krow[c + 48]);
      *(s16x4*)(Ks + kv * 64 + ((4 * c) ^ ((kv & 7) << 3))) = sv;
    }
#pragma unroll
    for (int p = 0; p < 4; ++p) {
      int f = tid + p * 256;
      int kv = f >> 4;
      int c = f & 15;
      f32x4 v = *(const f32x4*)(Vp + (size_t)(kv0 + kv) * Dd + 4 * c);
      int pv = (kv & 15) * 4 + (kv >> 4);
#pragma unroll
      for (int i = 0; i < 4; ++i) {
        int d = 4 * c + i;
        Vs[d * 64 + (pv ^ ((d & 7) << 3))] = f2bf(v[i]);
      }
    }
    __syncthreads();

    s16x8 kf[4][2];
#pragma unroll
    for (int sub = 0; sub < 4; ++sub) {
      int row = sub * 16 + l15;
      const short* base = Ks + row * 64;
      int sw = (row & 7) << 3;
      kf[sub][0] = *(const s16x8*)(base + ((16 * lq + 0) ^ sw));
      kf[sub][1] = *(const s16x8*)(base + ((16 * lq + 8) ^ sw));
    }
    s16x8 vf[4][2];
#pragma unroll
    for (int ds = 0; ds < 4; ++ds) {
      int row = ds * 16 + l15;
      const short* base = Vs + row * 64;
      int sw = (row & 7) << 3;
      vf[ds][0] = *(const s16x8*)(base + ((16 * lq + 0) ^ sw));
      vf[ds][1] = *(const s16x8*)(base + ((16 * lq + 8) ^ sw));
    }

    const int kvw = kv0 >> 6;
#pragma unroll
    for (int qs = 0; qs < 4; ++qs) {
      f32x4 sc[4];
#pragma unroll
      for (int sub = 0; sub < 4; ++sub) {
        f32x4 a = f32x4{0.f, 0.f, 0.f, 0.f};
        a = __builtin_amdgcn_mfma_f32_16x16x32_bf16(kf[sub][0], qf[qs][0], a, 0, 0, 0);
        a = __builtin_amdgcn_mfma_f32_16x16x32_bf16(kf[sub][1], qf[qs][1], a, 0, 0, 0);
        sc[sub] = a;
      }

      const int q = qbW + qs * 16 + l15;
      unsigned long long mw = 0;
      if constexpr (USEBITS) mw = mbits[(size_t)(b * Ss + q) * 32 + kvw];

      float tm = -3e38f;
#pragma unroll
      for (int sub = 0; sub < 4; ++sub) {
        f32x4 s = sc[sub];
        if constexpr (USEBITS) {
          unsigned nib = (unsigned)((mw >> (16 * sub + 4 * lq)) & 0xFULL);
#pragma unroll
          for (int r = 0; r < 4; ++r) {
            float sv = s[r] * SCALE;
            sv = ((nib >> r) & 1u) ? sv : -1e9f;
            s[r] = sv;
            tm = fmaxf(tm, sv);
          }
        } else {
          const int* mrow = mask + ((size_t)b * Ss + q) * Ss + kv0 + 16 * sub + 4 * lq;
          int4 mi = *(const int4*)mrow;
          int mv[4] = {mi.x, mi.y, mi.z, mi.w};
#pragma unroll
          for (int r = 0; r < 4; ++r) {
            float sv = s[r] * SCALE;
            sv = mv[r] ? sv : -1e9f;
            s[r] = sv;
            tm = fmaxf(tm, sv);
          }
        }
        sc[sub] = s;
      }
      tm = fmaxf(tm, __shfl_xor(tm, 16));
      tm = fmaxf(tm, __shfl_xor(tm, 32));
      float mnew = fmaxf(mrun[qs], tm);
      float corr = __expf(mrun[qs] - mnew);
      mrun[qs] = mnew;

      float ps = 0.f;
#pragma unroll
      for (int sub = 0; sub < 4; ++sub) {
        f32x4 s = sc[sub];
#pragma unroll
        for (int r = 0; r < 4; ++r) {
          float p = __expf(s[r] - mnew);
          s[r] = p;
          ps += p;
        }
        sc[sub] = s;
      }
      ps += __shfl_xor(ps, 16);
      ps += __shfl_xor(ps, 32);
      lrun[qs] = lrun[qs] * corr + ps;
#pragma unroll
      for (int ds = 0; ds < 4; ++ds) oacc[qs][ds] *= corr;

      s16x8 pf[2];
#pragma unroll
      for (int kvh = 0; kvh < 2; ++kvh) {
        s16x8 f;
#pragma unroll
        for (int j = 0; j < 8; ++j) f[j] = f2bf(sc[j & 3][2 * kvh + (j >> 2)]);
        pf[kvh] = f;
      }
#pragma unroll
      for (int ds = 0; ds < 4; ++ds) {
        f32x4 a = oacc[qs][ds];
        a = __builtin_amdgcn_mfma_f32_16x16x32_bf16(vf[ds][0], pf[0], a, 0, 0, 0);
        a = __builtin_amdgcn_mfma_f32_16x16x32_bf16(vf[ds][1], pf[1], a, 0, 0, 0);
        oacc[qs][ds] = a;
      }
    }
  }

#pragma unroll
  for (int qs = 0; qs < 4; ++qs) {
    float inv = 1.f / lrun[qs];
    float* orow = Op + (size_t)(qbW + qs * 16 + l15) * Dd;
#pragma unroll
    for (int ds = 0; ds < 4; ++ds) {
      f32x4 v = oacc[qs][ds];
      v *= inv;
      *(f32x4*)(orow + ds * 16 + 4 * lq) = v;
    }
  }
}

extern "C" void kernel_launch(void* const* d_in, const int* in_sizes, int n_in,
                              void* d_out, int out_size, void* d_ws, size_t ws_size,
                              hipStream_t stream) {
  const float* Q = (const float*)d_in[0];
  const float* K = (const float*)d_in[1];
  const float* V = (const float*)d_in[2];
  const int* mask = (const int*)d_in[5];
  float* out = (float*)d_out;

  const int nmask = Bb * Ss * Ss;
  const size_t bitsB = (size_t)(nmask / 64) * 8;          // 2 MiB
  const size_t imgB = (size_t)Bb * Hh * 32 * 4096 * 2;    // 16 MiB each
  const size_t need = bitsB + 2 * imgB;                   // 34 MiB

  if (d_ws && ws_size >= need) {
    unsigned long long* bits = (unsigned long long*)d_ws;
    short* Kimg = (short*)((char*)d_ws + bitsB);
    short* Vimg = (short*)((char*)d_ws + bitsB + imgB);
    prep<<<5120, 256, 0, stream>>>(K, V, mask, Kimg, Vimg, bits);
    attn3<<<512, 256, 0, stream>>>(Q, bits, Kimg, Vimg, out);
  } else if (d_ws && ws_size >= bitsB) {
    unsigned long long* bits = (unsigned long long*)d_ws;
    mask_to_bits<<<2048, 256, 0, stream>>>(mask, bits, nmask);
    attn_fwd<true><<<Bb * Hh * (Ss / 256), 256, 0, stream>>>(Q, K, V, mask, bits, out);
  } else {
    attn_fwd<false><<<Bb * Hh * (Ss / 256), 256, 0, stream>>>(Q, K, V, mask, nullptr, out);
  }
}

// Round 8
// 139.836 us; speedup vs baseline: 1.1486x; 1.1486x over previous
//
#include <hip/hip_runtime.h>
#include <stdint.h>

#define DEVINL __device__ __forceinline__

typedef float f32x4 __attribute__((ext_vector_type(4)));
typedef float f32x2 __attribute__((ext_vector_type(2)));
typedef short s16x8 __attribute__((ext_vector_type(8)));
typedef short s16x4 __attribute__((ext_vector_type(4)));
typedef unsigned int u32x4 __attribute__((ext_vector_type(4)));

constexpr int Bb = 4, Hh = 16, Ss = 2048, Dd = 64;
constexpr float SCALE = 0.088388347648318447f;                     // 1/sqrt(128)
constexpr float QSC = 0.088388347648318447f * 1.4426950408889634f; // scale * log2(e)

DEVINL short f2bf(float x) {
  union { float f; unsigned u; } c; c.f = x;
  unsigned r = (c.u + 0x7fffu + ((c.u >> 16) & 1u)) >> 16;  // RNE
  return (short)r;
}

DEVINL unsigned pkbf(float a, float b) {
  unsigned r;
  asm("v_cvt_pk_bf16_f32 %0, %1, %2" : "=v"(r) : "v"(a), "v"(b));
  return r;
}

DEVINL void gload_lds16(const short* g, short* l) {
  __builtin_amdgcn_global_load_lds(
      (const __attribute__((address_space(1))) void*)g,
      (__attribute__((address_space(3))) void*)l, 16, 0, 0);
}

// ---------------- fused prepass: K/V tile images + mask bitmask ----------------
// blocks [0,4096): K/V -> swizzled bf16 tile images (R4-proven layout)
//   K tile (bh,t): short[4096]; (kv,d) at kv*64 + ((4*(d&15) + (d>>4)) ^ ((kv&7)<<3))
//   V tile (bh,t): short[4096]; (d,kv) at d*64  + ((4*(kv&15) + (kv>>4)) ^ ((d&7)<<3))
// blocks [4096,5120): mask -> bitmask (64 ints -> one u64, bit i = keep)
__global__ void prep(const float* __restrict__ K, const float* __restrict__ V,
                     const int* __restrict__ mask,
                     short* __restrict__ Kimg, short* __restrict__ Vimg,
                     unsigned long long* __restrict__ bits) {
  const int x = blockIdx.x;
  const int tid = threadIdx.x;
  if (x < 4096) {
    const int sel = x & 1;
    const int t = (x >> 1) & 31;
    const int bh = x >> 6;
    if (sel == 0) {
      const float* Kp = K + ((size_t)bh * Ss + t * 64) * Dd;
      short* img = Kimg + ((size_t)bh * 32 + t) * 4096;
#pragma unroll
      for (int it = 0; it < 4; ++it) {
        int idx = tid + it * 256;
        int kv = idx >> 4, c = idx & 15;
        const float* kr = Kp + (size_t)kv * Dd;
        s16x4 sv;
        sv[0] = f2bf(kr[c]);
        sv[1] = f2bf(kr[c + 16]);
        sv[2] = f2bf(kr[c + 32]);
        sv[3] = f2bf(kr[c + 48]);
        *(s16x4*)(img + kv * 64 + ((4 * c) ^ ((kv & 7) << 3))) = sv;
      }
    } else {
      const float* Vp = V + ((size_t)bh * Ss + t * 64) * Dd;
      short* img = Vimg + ((size_t)bh * 32 + t) * 4096;
      const int d = tid & 63, c4 = tid >> 6;
#pragma unroll
      for (int it = 0; it < 4; ++it) {
        int c = c4 * 4 + it;
        s16x4 sv;
        sv[0] = f2bf(Vp[(size_t)(c) * Dd + d]);
        sv[1] = f2bf(Vp[(size_t)(c + 16) * Dd + d]);
        sv[2] = f2bf(Vp[(size_t)(c + 32) * Dd + d]);
        sv[3] = f2bf(Vp[(size_t)(c + 48) * Dd + d]);
        *(s16x4*)(img + d * 64 + ((4 * c) ^ ((d & 7) << 3))) = sv;
      }
    }
  } else {
    const int gid = (x - 4096) * 256 + tid;
    const int stride = 1024 * 256;
    const int n = Bb * Ss * Ss;
    for (int i = gid; i < n; i += stride) {
      unsigned long long bal = __ballot(mask[i] != 0);
      if ((i & 63) == 0) bits[i >> 6] = bal;
    }
  }
}

// ---------------- main attention kernel (R4 numerics, de-phased schedule) ----
// 4 waves x 32 q-rows (q-tile 128), grid 1024 -> 4-5 blocks/CU.
// Mask folded into QK^T C-init (bias 0 keep / -1e9 drop, log2 domain) -- the
// R4-PROVEN path. Schedule de-phased: exp2(qs0) trails QK^T subs, exp2(qs1)
// interleaves with PV(qs0), so matrix/trans/VALU pipes co-issue.
__launch_bounds__(256, 4)
__global__ void attn2(const float* __restrict__ Q,
                      const unsigned long long* __restrict__ mbits,
                      const short* __restrict__ Kimg,
                      const short* __restrict__ Vimg,
                      float* __restrict__ Out) {
  __shared__ short lds[16384];  // 2 bufs x (K 4096 | V 4096) shorts = 32 KB

  const int tid = threadIdx.x;
  const int lane = tid & 63;
  const int w = tid >> 6;
  const int l15 = lane & 15;
  const int lq = lane >> 4;

  const int bid = blockIdx.x;
  const int h = bid & 15;
  const int qt = (bid >> 4) & 15;
  const int b = bid >> 8;
  const int bh = b * Hh + h;

  const float* Qp = Q + (size_t)bh * Ss * Dd;
  float* Op = Out + (size_t)bh * Ss * Dd;
  const short* Kt = Kimg + (size_t)bh * 32 * 4096;
  const short* Vt = Vimg + (size_t)bh * 32 * 4096;
  const int qbW = qt * 128 + w * 32;

  // Q fragments (B-operand), scale*log2e folded in
  s16x8 qf[2][2];
#pragma unroll
  for (int qs = 0; qs < 2; ++qs) {
    const float* qrow = Qp + (size_t)(qbW + qs * 16 + l15) * Dd;
#pragma unroll
    for (int dh = 0; dh < 2; ++dh) {
      s16x8 f;
#pragma unroll
      for (int g = 0; g < 4; ++g) {
        f32x2 v = *(const f32x2*)(qrow + 16 * g + 4 * lq + 2 * dh);
        f[g] = f2bf(v[0] * QSC);
        f[g + 4] = f2bf(v[1] * QSC);
      }
      qf[qs][dh] = f;
    }
  }

  // constant ones A-fragment: row 0 = 1.0bf16, rows 1..15 = 0 (k-map agnostic)
  s16x8 onesA;
  {
    short o = (l15 == 0) ? (short)0x3F80 : (short)0;
#pragma unroll
    for (int j = 0; j < 8; ++j) onesA[j] = o;
  }

  f32x4 oacc[2][4];
  f32x4 lacc[2];
#pragma unroll
  for (int qs = 0; qs < 2; ++qs) {
    lacc[qs] = f32x4{0.f, 0.f, 0.f, 0.f};
#pragma unroll
    for (int ds = 0; ds < 4; ++ds) oacc[qs][ds] = f32x4{0.f, 0.f, 0.f, 0.f};
  }

  // loop-invariant fragment offsets (identical for K and V images)
  int off[4][2];
#pragma unroll
  for (int sub = 0; sub < 4; ++sub) {
    int row = sub * 16 + l15;
    int sw = (row & 7) << 3;
    off[sub][0] = row * 64 + ((16 * lq) ^ sw);
    off[sub][1] = row * 64 + ((16 * lq + 8) ^ sw);
  }

  const unsigned long long* mbq[2];
#pragma unroll
  for (int qs = 0; qs < 2; ++qs)
    mbq[qs] = mbits + (size_t)(b * Ss + qbW + qs * 16 + l15) * 32;

  auto stage = [&](int buf, int t) {
    short* Lb = lds + buf * 8192;
    const short* gk = Kt + t * 4096 + w * 512 + lane * 8;
    const short* gv = Vt + t * 4096 + w * 512 + lane * 8;
    gload_lds16(gk, Lb + w * 512);
    gload_lds16(gk + 2048, Lb + 2048 + w * 512);
    gload_lds16(gv, Lb + 4096 + w * 512);
    gload_lds16(gv + 2048, Lb + 6144 + w * 512);
  };

  stage(0, 0);

  for (int t = 0; t < 32; ++t) {
    const int cur = t & 1;
    unsigned long long mw0 = mbq[0][t];
    unsigned long long mw1 = mbq[1][t];
    __syncthreads();  // drains vmcnt -> buf[cur] ready; prev reads done
    if (t < 31) stage(cur ^ 1, t + 1);

    const short* kb = lds + cur * 8192;
    const short* vb = kb + 4096;

    // ---- mask bias (R4-proven): keep-bit=1 -> 0, bit=0 -> -1e9
    f32x4 bias0[4], bias1[4];
    {
      const unsigned mlo0 = ~(unsigned)(mw0 >> (4 * lq));
      const unsigned mhi0 = ~(unsigned)(mw0 >> (32 + 4 * lq));
      const unsigned mlo1 = ~(unsigned)(mw1 >> (4 * lq));
      const unsigned mhi1 = ~(unsigned)(mw1 >> (32 + 4 * lq));
#pragma unroll
      for (int sub = 0; sub < 4; ++sub) {
        const unsigned w0 = (sub < 2) ? mlo0 : mhi0;
        const unsigned w1 = (sub < 2) ? mlo1 : mhi1;
        const int base = 16 * (sub & 1);
#pragma unroll
        for (int r = 0; r < 4; ++r) {
          int s0 = ((int)(w0 << (31 - (base + r)))) >> 31;  // keep -> 0, drop -> -1
          int s1 = ((int)(w1 << (31 - (base + r)))) >> 31;
          bias0[sub][r] = __uint_as_float((unsigned)s0 & 0xCE6E6B28u);  // 0 or -1e9
          bias1[sub][r] = __uint_as_float((unsigned)s1 & 0xCE6E6B28u);
        }
      }
    }

    // ---- QK^T both qs (bias C-init); exp2(qs0) trails by one sub
    f32x4 sc0[4], sc1[4];
    __builtin_amdgcn_s_setprio(1);
#pragma unroll
    for (int sub = 0; sub < 4; ++sub) {
      s16x8 k0 = *(const s16x8*)(kb + off[sub][0]);
      s16x8 k1 = *(const s16x8*)(kb + off[sub][1]);
      f32x4 a0 = __builtin_amdgcn_mfma_f32_16x16x32_bf16(k0, qf[0][0], bias0[sub], 0, 0, 0);
      sc0[sub] = __builtin_amdgcn_mfma_f32_16x16x32_bf16(k1, qf[0][1], a0, 0, 0, 0);
      f32x4 a1 = __builtin_amdgcn_mfma_f32_16x16x32_bf16(k0, qf[1][0], bias1[sub], 0, 0, 0);
      sc1[sub] = __builtin_amdgcn_mfma_f32_16x16x32_bf16(k1, qf[1][1], a1, 0, 0, 0);
      if (sub > 0) {
        f32x4 s = sc0[sub - 1];
#pragma unroll
        for (int r = 0; r < 4; ++r) s[r] = __builtin_amdgcn_exp2f(s[r]);
        sc0[sub - 1] = s;
      }
    }
    __builtin_amdgcn_s_setprio(0);
    {
      f32x4 s = sc0[3];
#pragma unroll
      for (int r = 0; r < 4; ++r) s[r] = __builtin_amdgcn_exp2f(s[r]);
      sc0[3] = s;
    }

    // ---- pack qs0 (bias already masked the scores), PV(qs0) ∥ exp2(qs1)
    s16x8 pf0[2];
#pragma unroll
    for (int kvh = 0; kvh < 2; ++kvh) {
      u32x4 wv;
      wv[0] = pkbf(sc0[0][2 * kvh], sc0[1][2 * kvh]);
      wv[1] = pkbf(sc0[2][2 * kvh], sc0[3][2 * kvh]);
      wv[2] = pkbf(sc0[0][2 * kvh + 1], sc0[1][2 * kvh + 1]);
      wv[3] = pkbf(sc0[2][2 * kvh + 1], sc0[3][2 * kvh + 1]);
      pf0[kvh] = __builtin_bit_cast(s16x8, wv);
    }
    __builtin_amdgcn_s_setprio(1);
#pragma unroll
    for (int ds = 0; ds < 4; ++ds) {
      s16x8 v0 = *(const s16x8*)(vb + off[ds][0]);
      s16x8 v1 = *(const s16x8*)(vb + off[ds][1]);
      f32x4 a = oacc[0][ds];
      a = __builtin_amdgcn_mfma_f32_16x16x32_bf16(v0, pf0[0], a, 0, 0, 0);
      oacc[0][ds] = __builtin_amdgcn_mfma_f32_16x16x32_bf16(v1, pf0[1], a, 0, 0, 0);
      f32x4 s = sc1[ds];
#pragma unroll
      for (int r = 0; r < 4; ++r) s[r] = __builtin_amdgcn_exp2f(s[r]);
      sc1[ds] = s;
    }
    lacc[0] = __builtin_amdgcn_mfma_f32_16x16x32_bf16(onesA, pf0[0], lacc[0], 0, 0, 0);
    lacc[0] = __builtin_amdgcn_mfma_f32_16x16x32_bf16(onesA, pf0[1], lacc[0], 0, 0, 0);
    __builtin_amdgcn_s_setprio(0);

    // ---- pack qs1, PV(qs1)
    s16x8 pf1[2];
#pragma unroll
    for (int kvh = 0; kvh < 2; ++kvh) {
      u32x4 wv;
      wv[0] = pkbf(sc1[0][2 * kvh], sc1[1][2 * kvh]);
      wv[1] = pkbf(sc1[2][2 * kvh], sc1[3][2 * kvh]);
      wv[2] = pkbf(sc1[0][2 * kvh + 1], sc1[1][2 * kvh + 1]);
      wv[3] = pkbf(sc1[2][2 * kvh + 1], sc1[3][2 * kvh + 1]);
      pf1[kvh] = __builtin_bit_cast(s16x8, wv);
    }
    __builtin_amdgcn_s_setprio(1);
#pragma unroll
    for (int ds = 0; ds < 4; ++ds) {
      s16x8 v0 = *(const s16x8*)(vb + off[ds][0]);
      s16x8 v1 = *(const s16x8*)(vb + off[ds][1]);
      f32x4 a = oacc[1][ds];
      a = __builtin_amdgcn_mfma_f32_16x16x32_bf16(v0, pf1[0], a, 0, 0, 0);
      oacc[1][ds] = __builtin_amdgcn_mfma_f32_16x16x32_bf16(v1, pf1[1], a, 0, 0, 0);
    }
    lacc[1] = __builtin_amdgcn_mfma_f32_16x16x32_bf16(onesA, pf1[0], lacc[1], 0, 0, 0);
    lacc[1] = __builtin_amdgcn_mfma_f32_16x16x32_bf16(onesA, pf1[1], lacc[1], 0, 0, 0);
    __builtin_amdgcn_s_setprio(0);
  }

  // epilogue: l lives in row 0 (lanes lq==0, reg 0); broadcast, divide, store
#pragma unroll
  for (int qs = 0; qs < 2; ++qs) {
    float l = __shfl(lacc[qs][0], l15);  // lane l15 holds l for q-col l15
    float inv = 1.f / l;
    float* orow = Op + (size_t)(qbW + qs * 16 + l15) * Dd;
#pragma unroll
    for (int ds = 0; ds < 4; ++ds) {
      f32x4 v = oacc[qs][ds];
      v *= inv;
      *(f32x4*)(orow + ds * 16 + 4 * lq) = v;
    }
  }
}

// ---------------- fallback (round-1 kernel, proven) ----------------
__global__ void mask_to_bits(const int* __restrict__ mask,
                             unsigned long long* __restrict__ bits, int n) {
  int gid = blockIdx.x * blockDim.x + threadIdx.x;
  int stride = gridDim.x * blockDim.x;
  for (int i = gid; i < n; i += stride) {
    unsigned long long bal = __ballot(mask[i] != 0);
    if ((i & 63) == 0) bits[i >> 6] = bal;
  }
}

template<bool USEBITS>
__launch_bounds__(256, 2)
__global__ void attn_fwd(const float* __restrict__ Q, const float* __restrict__ K,
                         const float* __restrict__ V, const int* __restrict__ mask,
                         const unsigned long long* __restrict__ mbits,
                         float* __restrict__ Out) {
  __shared__ short Ks[64 * 64];
  __shared__ short Vs[64 * 64];

  const int tid = threadIdx.x;
  const int lane = tid & 63;
  const int w = tid >> 6;
  const int l15 = lane & 15;
  const int lq = lane >> 4;

  const int bid = blockIdx.x;
  const int h = bid & 15;
  const int qt = (bid >> 4) & 7;
  const int b = bid >> 7;

  const int bh = b * Hh + h;
  const float* Qp = Q + (size_t)bh * Ss * Dd;
  const float* Kp = K + (size_t)bh * Ss * Dd;
  const float* Vp = V + (size_t)bh * Ss * Dd;
  float* Op = Out + (size_t)bh * Ss * Dd;

  const int qbW = qt * 256 + w * 64;

  s16x8 qf[4][2];
#pragma unroll
  for (int qs = 0; qs < 4; ++qs) {
    const float* qrow = Qp + (size_t)(qbW + qs * 16 + l15) * Dd;
#pragma unroll
    for (int dh = 0; dh < 2; ++dh) {
      s16x8 f;
#pragma unroll
      for (int g = 0; g < 4; ++g) {
        f32x2 v = *(const f32x2*)(qrow + 16 * g + 4 * lq + 2 * dh);
        f[g] = f2bf(v[0]);
        f[g + 4] = f2bf(v[1]);
      }
      qf[qs][dh] = f;
    }
  }

  f32x4 oacc[4][4];
  float mrun[4], lrun[4];
#pragma unroll
  for (int qs = 0; qs < 4; ++qs) {
    mrun[qs] = -1e30f;
    lrun[qs] = 0.f;
#pragma unroll
    for (int ds = 0; ds < 4; ++ds) oacc[qs][ds] = f32x4{0.f, 0.f, 0.f, 0.f};
  }

  for (int kv0 = 0; kv0 < Ss; kv0 += 64) {
    __syncthreads();
#pragma unroll
    for (int p = 0; p < 4; ++p) {
      int f = tid + p * 256;
      int kv = f >> 4;
      int c = f & 15;
      const float* krow = Kp + (size_t)(kv0 + kv) * Dd;
      s16x4 sv;
      sv[0] = f2bf(krow[c]);
      sv[1] = f2bf(krow[c + 16]);
      sv[2] = f2bf(krow[c + 32]);
      sv[3] = f2bf(krow[c + 48]);
      *(s16x4*)(Ks + kv * 64 + ((4 * c) ^ ((kv & 7) << 3))) = sv;
    }
#pragma unroll
    for (int p = 0; p < 4; ++p) {
      int f = tid + p * 256;
      int kv = f >> 4;
      int c = f & 15;
      f32x4 v = *(const f32x4*)(Vp + (size_t)(kv0 + kv) * Dd + 4 * c);
      int pv = (kv & 15) * 4 + (kv >> 4);
#pragma unroll
      for (int i = 0; i < 4; ++i) {
        int d = 4 * c + i;
        Vs[d * 64 + (pv ^ ((d & 7) << 3))] = f2bf(v[i]);
      }
    }
    __syncthreads();

    s16x8 kf[4][2];
#pragma unroll
    for (int sub = 0; sub < 4; ++sub) {
      int row = sub * 16 + l15;
      const short* base = Ks + row * 64;
      int sw = (row & 7) << 3;
      kf[sub][0] = *(const s16x8*)(base + ((16 * lq + 0) ^ sw));
      kf[sub][1] = *(const s16x8*)(base + ((16 * lq + 8) ^ sw));
    }
    s16x8 vf[4][2];
#pragma unroll
    for (int ds = 0; ds < 4; ++ds) {
      int row = ds * 16 + l15;
      const short* base = Vs + row * 64;
      int sw = (row & 7) << 3;
      vf[ds][0] = *(const s16x8*)(base + ((16 * lq + 0) ^ sw));
      vf[ds][1] = *(const s16x8*)(base + ((16 * lq + 8) ^ sw));
    }

    const int kvw = kv0 >> 6;
#pragma unroll
    for (int qs = 0; qs < 4; ++qs) {
      f32x4 sc[4];
#pragma unroll
      for (int sub = 0; sub < 4; ++sub) {
        f32x4 a = f32x4{0.f, 0.f, 0.f, 0.f};
        a = __builtin_amdgcn_mfma_f32_16x16x32_bf16(kf[sub][0], qf[qs][0], a, 0, 0, 0);
        a = __builtin_amdgcn_mfma_f32_16x16x32_bf16(kf[sub][1], qf[qs][1], a, 0, 0, 0);
        sc[sub] = a;
      }

      const int q = qbW + qs * 16 + l15;
      unsigned long long mw = 0;
      if constexpr (USEBITS) mw = mbits[(size_t)(b * Ss + q) * 32 + kvw];

      float tm = -3e38f;
#pragma unroll
      for (int sub = 0; sub < 4; ++sub) {
        f32x4 s = sc[sub];
        if constexpr (USEBITS) {
          unsigned nib = (unsigned)((mw >> (16 * sub + 4 * lq)) & 0xFULL);
#pragma unroll
          for (int r = 0; r < 4; ++r) {
            float sv = s[r] * SCALE;
            sv = ((nib >> r) & 1u) ? sv : -1e9f;
            s[r] = sv;
            tm = fmaxf(tm, sv);
          }
        } else {
          const int* mrow = mask + ((size_t)b * Ss + q) * Ss + kv0 + 16 * sub + 4 * lq;
          int4 mi = *(const int4*)mrow;
          int mv[4] = {mi.x, mi.y, mi.z, mi.w};
#pragma unroll
          for (int r = 0; r < 4; ++r) {
            float sv = s[r] * SCALE;
            sv = mv[r] ? sv : -1e9f;
            s[r] = sv;
            tm = fmaxf(tm, sv);
          }
        }
        sc[sub] = s;
      }
      tm = fmaxf(tm, __shfl_xor(tm, 16));
      tm = fmaxf(tm, __shfl_xor(tm, 32));
      float mnew = fmaxf(mrun[qs], tm);
      float corr = __expf(mrun[qs] - mnew);
      mrun[qs] = mnew;

      float ps = 0.f;
#pragma unroll
      for (int sub = 0; sub < 4; ++sub) {
        f32x4 s = sc[sub];
#pragma unroll
        for (int r = 0; r < 4; ++r) {
          float p = __expf(s[r] - mnew);
          s[r] = p;
          ps += p;
        }
        sc[sub] = s;
      }
      ps += __shfl_xor(ps, 16);
      ps += __shfl_xor(ps, 32);
      lrun[qs] = lrun[qs] * corr + ps;
#pragma unroll
      for (int ds = 0; ds < 4; ++ds) oacc[qs][ds] *= corr;

      s16x8 pf[2];
#pragma unroll
      for (int kvh = 0; kvh < 2; ++kvh) {
        s16x8 f;
#pragma unroll
        for (int j = 0; j < 8; ++j) f[j] = f2bf(sc[j & 3][2 * kvh + (j >> 2)]);
        pf[kvh] = f;
      }
#pragma unroll
      for (int ds = 0; ds < 4; ++ds) {
        f32x4 a = oacc[qs][ds];
        a = __builtin_amdgcn_mfma_f32_16x16x32_bf16(vf[ds][0], pf[0], a, 0, 0, 0);
        a = __builtin_amdgcn_mfma_f32_16x16x32_bf16(vf[ds][1], pf[1], a, 0, 0, 0);
        oacc[qs][ds] = a;
      }
    }
  }

#pragma unroll
  for (int qs = 0; qs < 4; ++qs) {
    float inv = 1.f / lrun[qs];
    float* orow = Op + (size_t)(qbW + qs * 16 + l15) * Dd;
#pragma unroll
    for (int ds = 0; ds < 4; ++ds) {
      f32x4 v = oacc[qs][ds];
      v *= inv;
      *(f32x4*)(orow + ds * 16 + 4 * lq) = v;
    }
  }
}

extern "C" void kernel_launch(void* const* d_in, const int* in_sizes, int n_in,
                              void* d_out, int out_size, void* d_ws, size_t ws_size,
                              hipStream_t stream) {
  const float* Q = (const float*)d_in[0];
  const float* K = (const float*)d_in[1];
  const float* V = (const float*)d_in[2];
  const int* mask = (const int*)d_in[5];
  float* out = (float*)d_out;

  const int nmask = Bb * Ss * Ss;
  const size_t bitsB = (size_t)(nmask / 64) * 8;          // 2 MiB
  const size_t imgB = (size_t)Bb * Hh * 32 * 4096 * 2;    // 16 MiB each
  const size_t need = bitsB + 2 * imgB;                   // 34 MiB

  if (d_ws && ws_size >= need) {
    unsigned long long* bits = (unsigned long long*)d_ws;
    short* Kimg = (short*)((char*)d_ws + bitsB);
    short* Vimg = (short*)((char*)d_ws + bitsB + imgB);
    prep<<<5120, 256, 0, stream>>>(K, V, mask, Kimg, Vimg, bits);
    attn2<<<Bb * Hh * (Ss / 128), 256, 0, stream>>>(Q, bits, Kimg, Vimg, out);
  } else if (d_ws && ws_size >= bitsB) {
    unsigned long long* bits = (unsigned long long*)d_ws;
    mask_to_bits<<<2048, 256, 0, stream>>>(mask, bits, nmask);
    attn_fwd<true><<<Bb * Hh * (Ss / 256), 256, 0, stream>>>(Q, K, V, mask, bits, out);
  } else {
    attn_fwd<false><<<Bb * Hh * (Ss / 256), 256, 0, stream>>>(Q, K, V, mask, nullptr, out);
  }
}